// Round 8
// baseline (114.233 us; speedup 1.0000x reference)
//
#include <hip/hip_runtime.h>

// Signature_72327249265296: depth-4 path signature, path [64,512,10] fp32.
// out[b] = concat(A1[10], A2[100], A3[1000], A4[10000]).
//
// V7: 5-chains-per-thread (V4 math, PASSED) with accumulators in NAMED
// scalar registers. Post-mortem chain:
//   - V2 (1 chain/thr) = LDS-throughput-bound: d-row broadcast costs full
//     register-fill rate PER WAVE (~31cy/step/wave) -> ~41us floor. Any
//     LDS-broadcast design pays this; must amortize over chains/thread.
//   - V4/V5 (5 chains) collapsed because a4[5][10] was address-taken
//     (lambda ref-capture / pointer arg) -> scratch, not registers.
//   - V6 (readlane->SGPR) serialized on SGPR WAR + cross-lane latency.
// V7 fixes V4's execution: all 57 accumulators are macro-generated NAMED
// locals inside one templated __device__ function (epilogue included, no
// accumulator ever passed by address); k-selection compile-time via H.
// Geometry: NSEG=16 x SEGLEN=32 -> 1024 blocks x 4 waves = 4 waves/SIMD;
// __launch_bounds__(256,2) caps VGPR at 128 (est. demand ~100).
// Model: VALU ~70 inst/step -> 7.5us/SIMD; LDS ~37cy/step/wave -> 7.9us/CU.
// Chen per-step recurrence per chain (validated V1/V2/V4):
//   p1 = A1/6 + dxi/24 ; q1 = A1/2 + dxi/6 ; r1 = A1 + dxi/2
//   p2 = A2/2 + p1*dxj ; q2 = A2 + q1*dxj  ; A2 += r1*dxj
//   p3k = A3k + p2*dk  ; A3k += q2*dk      ; A1 += dxi ; A4[k][l] += p3k*d[l]
// Segment combine: serial Chen fold of NSEG partials (validated V2-V6).
// The ~42.5us 256MiB workspace poison is in the timed graph unconditionally
// (present in round 0 which used no ws) -> workspace use is free.

#define CH      10
#define NSTEPS  511
#define SIGSZ   11110
#define WSSEG   11112                    // per-partial stride (16B-aligned)
#define NSEG    16
#define SEGLEN  32
#define TRP     36                       // transposed LDS stride

#define DECL_CHAIN(m) \
    float a3_##m = 0.f; \
    float a4_##m##_0=0.f,a4_##m##_1=0.f,a4_##m##_2=0.f,a4_##m##_3=0.f, \
          a4_##m##_4=0.f,a4_##m##_5=0.f,a4_##m##_6=0.f,a4_##m##_7=0.f, \
          a4_##m##_8=0.f,a4_##m##_9=0.f;

#define CHAIN_STEP(m, dk) { \
    const float p3 = a3_##m + p2*(dk); a3_##m += q2*(dk); \
    a4_##m##_0 += p3*e0; a4_##m##_1 += p3*e1; a4_##m##_2 += p3*e2; \
    a4_##m##_3 += p3*e3; a4_##m##_4 += p3*e4; a4_##m##_5 += p3*e5; \
    a4_##m##_6 += p3*e6; a4_##m##_7 += p3*e7; a4_##m##_8 += p3*e8; \
    a4_##m##_9 += p3*e9; }

#define STORE_CHAIN(m, koff) { \
    float* o4 = ob + 1110 + (idbase + (koff))*10; \
    o4[0]=a4_##m##_0; o4[1]=a4_##m##_1; o4[2]=a4_##m##_2; o4[3]=a4_##m##_3; \
    o4[4]=a4_##m##_4; o4[5]=a4_##m##_5; o4[6]=a4_##m##_6; o4[7]=a4_##m##_7; \
    o4[8]=a4_##m##_8; o4[9]=a4_##m##_9; \
    ob[110 + idbase + (koff)] = a3_##m; }

template<int H>
__device__ __forceinline__ void run_half(const float* __restrict__ rowL,
                                         const float* __restrict__ trL,
                                         int ci, int cj, bool wr,
                                         float* __restrict__ ob) {
    float a1 = 0.f, a2 = 0.f;
    DECL_CHAIN(0) DECL_CHAIN(1) DECL_CHAIN(2) DECL_CHAIN(3) DECL_CHAIN(4)

    const float* ti = trL + ci * TRP;
    const float* tj = trL + cj * TRP;

    for (int s4 = 0; s4 < SEGLEN; s4 += 4) {
        const float4 vi = *(const float4*)(ti + s4);
        const float4 vj = *(const float4*)(tj + s4);
        const float* rp = rowL + s4 * 12;
        #pragma unroll
        for (int u = 0; u < 4; ++u) {
            const float4 dA = *(const float4*)(rp + u * 12);
            const float4 dB = *(const float4*)(rp + u * 12 + 4);
            const float2 dC = *(const float2*)(rp + u * 12 + 8);
            const float e0 = dA.x, e1 = dA.y, e2 = dA.z, e3 = dA.w;
            const float e4 = dB.x, e5 = dB.y, e6 = dB.z, e7 = dB.w;
            const float e8 = dC.x, e9 = dC.y;
            const float dxi = (u == 0) ? vi.x : (u == 1) ? vi.y
                             : (u == 2) ? vi.z : vi.w;
            const float dxj = (u == 0) ? vj.x : (u == 1) ? vj.y
                             : (u == 2) ? vj.z : vj.w;

            // shared (i,j) Horner prefix
            const float p1 = a1 * (1.f / 6.f) + dxi * (1.f / 24.f);
            const float q1 = a1 * 0.5f        + dxi * (1.f / 6.f);
            const float r1 = a1               + dxi * 0.5f;
            const float p2 = a2 * 0.5f + p1 * dxj;
            const float q2 = a2        + q1 * dxj;
            a2 += r1 * dxj;
            a1 += dxi;

            if (H == 0) {
                CHAIN_STEP(0, e0) CHAIN_STEP(1, e1) CHAIN_STEP(2, e2)
                CHAIN_STEP(3, e3) CHAIN_STEP(4, e4)
            } else {
                CHAIN_STEP(0, e5) CHAIN_STEP(1, e6) CHAIN_STEP(2, e7)
                CHAIN_STEP(3, e8) CHAIN_STEP(4, e9)
            }
        }
    }

    if (wr) {
        const int idbase = ci * 100 + cj * 10 + H * 5;
        STORE_CHAIN(0, 0) STORE_CHAIN(1, 1) STORE_CHAIN(2, 2)
        STORE_CHAIN(3, 3) STORE_CHAIN(4, 4)
        if (H == 0) {
            ob[10 + ci * 10 + cj] = a2;
            if (cj == 0) ob[ci] = a1;
        }
    }
}

__global__ __launch_bounds__(256, 2)
void sig_partial(const float* __restrict__ path, float* __restrict__ ws) {
    __shared__ __align__(16) float rowL[SEGLEN * 12];   // [s][c] padded rows
    __shared__ __align__(16) float trL[CH * TRP];       // [c][s] transposed

    const int tid = threadIdx.x;
    const int bx  = blockIdx.x;          // 1024 = 64 batches x 16 segments
    const int b   = bx >> 4;
    const int seg = bx & 15;
    const int s0  = seg * SEGLEN;

    // ---- stage this segment's increments into both LDS layouts ----
    const float* p = path + (size_t)b * (512 * CH) + s0 * CH;
    for (int e = tid; e < SEGLEN * CH; e += 256) {
        const int s = e / CH;
        const int c = e - s * CH;
        float v = 0.f;
        if (s0 + s < NSTEPS) v = p[e + CH] - p[e];   // seg 15 step 31 = 0 pad
        rowL[s * 12 + c] = v;
        trL[c * TRP + s] = v;
    }
    __syncthreads();

    // thread -> (i,j, k-half): tid 0..99 -> half 0, tid 128..227 -> half 1.
    // half = tid>>7 is wave-uniform (waves 0,1 vs waves 2,3).
    const int half = tid >> 7;
    const int ij   = tid & 127;
    const int ijc  = (ij < 100) ? ij : 99;   // tail threads run dummy, no write
    const int ci   = ijc / 10;
    const int cj   = ijc - ci * 10;
    const bool wr  = (ij < 100);

    float* ob = ws + (size_t)(b * NSEG + seg) * WSSEG;
    if (half == 0) run_half<0>(rowL, trL, ci, cj, wr, ob);
    else           run_half<1>(rowL, trL, ci, cj, wr, ob);
}

__global__ __launch_bounds__(256)
void sig_combine(const float* __restrict__ ws, float* __restrict__ out) {
    __shared__ float B[1110];             // levels 1-3 of one segment partial

    const int tid  = threadIdx.x;
    const int b    = blockIdx.x >> 2;
    const int part = blockIdx.x & 3;
    const int id   = part * 256 + tid;
    const bool valid = (id < 1000);

    const int ci = id / 100;
    const int cj = (id / 10) % 10;
    const int ck = id % 10;

    const float* w0 = ws + (size_t)b * NSEG * WSSEG;

    float a1 = 0.f, a2 = 0.f, a3 = 0.f;
    float a4[10];
    #pragma unroll
    for (int l = 0; l < 10; ++l) a4[l] = 0.f;
    if (valid) {
        a1 = w0[ci];
        a2 = w0[10 + ci * 10 + cj];
        a3 = w0[110 + id];
        #pragma unroll
        for (int l = 0; l < 10; ++l) a4[l] = w0[1110 + id * 10 + l];
    }

    for (int s = 1; s < NSEG; ++s) {
        const float* wb = w0 + (size_t)s * WSSEG;
        __syncthreads();                  // previous iter done reading B
        for (int e = tid; e < 1110; e += 256) B[e] = wb[e];
        __syncthreads();

        if (valid) {
            const float b1i   = B[ci];
            const float b1j   = B[cj];
            const float b1k   = B[ck];
            const float b2_ij = B[10 + ci * 10 + cj];
            const float b2_jk = B[10 + cj * 10 + ck];
            const float b3ijk = B[110 + id];

            float b4v[10];
            #pragma unroll
            for (int l = 0; l < 10; ++l) b4v[l] = wb[1110 + id * 10 + l];

            // Z4 uses OLD a1,a2,a3 (computed before lower levels update)
            #pragma unroll
            for (int l = 0; l < 10; ++l)
                a4[l] += a3 * B[l] + a2 * B[10 + ck * 10 + l]
                       + a1 * B[110 + (cj * 10 + ck) * 10 + l] + b4v[l];
            a3 += a2 * b1k + a1 * b2_jk + b3ijk;
            a2 += a1 * b1j + b2_ij;
            a1 += b1i;
        }
    }

    if (valid) {
        float* ob = out + (size_t)b * SIGSZ;
        float* o4 = ob + 1110 + id * 10;
        #pragma unroll
        for (int l = 0; l < 10; ++l) o4[l] = a4[l];
        ob[110 + id] = a3;
        if (ck == 0)            ob[10 + ci * 10 + cj] = a2;
        if (ck == 0 && cj == 0) ob[ci] = a1;
    }
}

extern "C" void kernel_launch(void* const* d_in, const int* in_sizes, int n_in,
                              void* d_out, int out_size, void* d_ws, size_t ws_size,
                              hipStream_t stream) {
    const float* path = (const float*)d_in[0];   // [64, 512, 10] fp32
    float* out = (float*)d_out;                  // [64, 11110] fp32
    float* ws  = (float*)d_ws;                   // 64*16*11112 floats = 45.5 MB

    sig_partial<<<dim3(1024), dim3(256), 0, stream>>>(path, ws);
    sig_combine<<<dim3(256),  dim3(256), 0, stream>>>(ws, out);
}

// Round 9
// 113.588 us; speedup vs baseline: 1.0057x; 1.0057x over previous
//
#include <hip/hip_runtime.h>

// Signature_72327249265296: depth-4 path signature, path [64,512,10] fp32.
// out[b] = concat(A1[10], A2[100], A3[1000], A4[10000]).
//
// V8: V2's proven 1-chain-per-thread loop (small state -> LDS loads pipeline,
// 40us measured, exactly matches the LDS-throughput model), with the
// wave-uniform d-row broadcast moved to the SCALAR pipe via inline-asm
// s_load_dwordx4 (forced -- V3 relied on uniformity analysis and never
// verifiably scalarized):
//   - sig_prep writes dx to global dxP[64][512][12] (48B rows, 16B-aligned,
//     1.5MB -> L2-resident; a block's segment rows ~6KB -> sKcache).
//   - per step: one asm block { 3x s_load_dwordx4 ; s_waitcnt lgkmcnt(0) }
//     from an SGPR base advanced 192B per 4 steps. d[l] live in SGPRs;
//     A4 FMAs are v_fmac_f32 v,s,v (1 SGPR operand -- legal).
//   - per-lane dxi/dxj/dxk from transposed trL, 3x ds_read_b128 per 4 steps
//     (9 LDS-cy/step/wave vs V2's 48 -- the 31cy/step broadcast is GONE).
//   - VALU becomes the bottleneck: ~24 inst/step -> 4096 waves x 128 steps
//     x 48cy / 1024 SIMD ~ 10us. 16 waves/CU TLP hides scalar-cache latency.
//   - 5-chain design abandoned: V4/V5/V7 (three implementations) all >=50us.
// Chen per-step recurrence (validated V1/V2/V4-V7):
//   p1 = A1/6 + dxi/24 ; q1 = A1/2 + dxi/6 ; r1 = A1 + dxi/2
//   p2 = A2/2 + p1*dxj ; q2 = A2 + q1*dxj  ; A2 += r1*dxj
//   p3 = A3 + p2*dxk   ; A3 += q2*dxk      ; A1 += dxi ; A4[l] += p3*d[l]
// Segment combine: serial Chen fold of NSEG=4 partials (validated V2-V7).
// The ~44us 256MiB workspace poison is in the timed graph unconditionally
// (present in round 0 which used no workspace) -> workspace use is free.

#define CH      10
#define NSTEPS  511
#define SIGSZ   11110
#define WSSEG   11112                    // per-partial stride (16B-aligned)
#define NSEG    4
#define SEGLEN  128
#define TRP     132                      // transposed LDS stride (16B-aligned)

#define DXP_OFF (64 * NSEG * WSSEG)      // float offset of dxP in workspace

typedef __attribute__((ext_vector_type(4))) float f32x4;

__global__ __launch_bounds__(256)
void sig_prep(const float* __restrict__ path, float* __restrict__ dxP) {
    const int nElem = 64 * 512 * 12;
    for (int e = blockIdx.x * 256 + threadIdx.x; e < nElem;
         e += gridDim.x * 256) {
        const int row = e / 12;
        const int c   = e - row * 12;
        const int b   = row >> 9;
        const int s   = row & 511;
        float v = 0.f;
        if (s < NSTEPS && c < CH) {
            const float* pp = path + ((size_t)b * 512 + s) * CH + c;
            v = pp[CH] - pp[0];
        }
        dxP[e] = v;
    }
}

__global__ __launch_bounds__(256)
void sig_partial(const float* __restrict__ path, const float* __restrict__ dxP,
                 float* __restrict__ ws) {
    __shared__ __align__(16) float trL[CH * TRP];   // [c][s] transposed dx

    const int tid  = threadIdx.x;
    const int bx   = blockIdx.x;          // 1024 = 64 batches x 4 seg x 4 parts
    const int b    = bx >> 4;
    const int seg  = (bx >> 2) & 3;
    const int part = bx & 3;
    const int s0   = seg * SEGLEN;

    // ---- stage transposed per-lane dx into LDS (from path, V2-proven) ----
    const float* p = path + (size_t)b * (512 * CH) + s0 * CH;
    for (int e = tid; e < SEGLEN * CH; e += 256) {
        const int s = e / CH;
        const int c = e - s * CH;
        float v = 0.f;
        if (s0 + s < NSTEPS) v = p[e + CH] - p[e];   // seg 3 step 127 = 0 pad
        trL[c * TRP + s] = v;
    }
    __syncthreads();

    const int id = part * 256 + tid;      // chain id = i*100 + j*10 + k
    if (id < 1000) {
        const int ci = id / 100;
        const int cj = (id / 10) % 10;
        const int ck = id % 10;

        float a1 = 0.f, a2 = 0.f, a3 = 0.f;
        float a4[10];
        #pragma unroll
        for (int l = 0; l < 10; ++l) a4[l] = 0.f;

        const float* ti = trL + ci * TRP;
        const float* tj = trL + cj * TRP;
        const float* tk = trL + ck * TRP;
        // wave-uniform scalar base for this segment's padded dx rows
        const float* dp = dxP + (size_t)(b * 512 + s0) * 12;

        for (int s4 = 0; s4 < SEGLEN; s4 += 4) {     // runtime loop, small body
            const float4 vi = *(const float4*)(ti + s4);
            const float4 vj = *(const float4*)(tj + s4);
            const float4 vk = *(const float4*)(tk + s4);
            #pragma unroll
            for (int u = 0; u < 4; ++u) {
                // d-row for this step -> SGPRs via forced scalar loads.
                f32x4 eA, eB, eC;
                asm volatile(
                    "s_load_dwordx4 %0, %3, %4\n\t"
                    "s_load_dwordx4 %1, %3, %5\n\t"
                    "s_load_dwordx4 %2, %3, %6\n\t"
                    "s_waitcnt lgkmcnt(0)"
                    : "=s"(eA), "=s"(eB), "=s"(eC)
                    : "s"(dp), "n"(u * 48), "n"(u * 48 + 16), "n"(u * 48 + 32));

                const float dxi = (u == 0) ? vi.x : (u == 1) ? vi.y
                                 : (u == 2) ? vi.z : vi.w;
                const float dxj = (u == 0) ? vj.x : (u == 1) ? vj.y
                                 : (u == 2) ? vj.z : vj.w;
                const float dxk = (u == 0) ? vk.x : (u == 1) ? vk.y
                                 : (u == 2) ? vk.z : vk.w;

                const float p1 = a1 * (1.f / 6.f) + dxi * (1.f / 24.f);
                const float q1 = a1 * 0.5f        + dxi * (1.f / 6.f);
                const float r1 = a1               + dxi * 0.5f;
                const float p2 = a2 * 0.5f + p1 * dxj;
                const float q2 = a2        + q1 * dxj;
                a2 += r1 * dxj;
                const float p3 = a3 + p2 * dxk;
                a3 += q2 * dxk;
                a1 += dxi;

                a4[0] += p3 * eA.x; a4[1] += p3 * eA.y;
                a4[2] += p3 * eA.z; a4[3] += p3 * eA.w;
                a4[4] += p3 * eB.x; a4[5] += p3 * eB.y;
                a4[6] += p3 * eB.z; a4[7] += p3 * eB.w;
                a4[8] += p3 * eC.x; a4[9] += p3 * eC.y;
            }
            dp += 48;                     // 4 rows x 48B, stays in SGPRs
        }

        // ---- epilogue: write this chain's share of the segment partial ----
        float* ob = ws + (size_t)(b * NSEG + seg) * WSSEG;
        float* o4 = ob + 1110 + id * 10;
        #pragma unroll
        for (int l = 0; l < 10; ++l) o4[l] = a4[l];
        ob[110 + id] = a3;
        if (ck == 0)            ob[10 + ci * 10 + cj] = a2;
        if (ck == 0 && cj == 0) ob[ci] = a1;
    }
}

__global__ __launch_bounds__(256)
void sig_combine(const float* __restrict__ ws, float* __restrict__ out) {
    __shared__ float B[1110];             // levels 1-3 of one segment partial

    const int tid  = threadIdx.x;
    const int b    = blockIdx.x >> 2;
    const int part = blockIdx.x & 3;
    const int id   = part * 256 + tid;
    const bool valid = (id < 1000);

    const int ci = id / 100;
    const int cj = (id / 10) % 10;
    const int ck = id % 10;

    const float* w0 = ws + (size_t)b * NSEG * WSSEG;

    float a1 = 0.f, a2 = 0.f, a3 = 0.f;
    float a4[10];
    #pragma unroll
    for (int l = 0; l < 10; ++l) a4[l] = 0.f;
    if (valid) {
        a1 = w0[ci];
        a2 = w0[10 + ci * 10 + cj];
        a3 = w0[110 + id];
        #pragma unroll
        for (int l = 0; l < 10; ++l) a4[l] = w0[1110 + id * 10 + l];
    }

    for (int s = 1; s < NSEG; ++s) {
        const float* wb = w0 + (size_t)s * WSSEG;
        __syncthreads();                  // previous iter done reading B
        for (int e = tid; e < 1110; e += 256) B[e] = wb[e];
        __syncthreads();

        if (valid) {
            const float b1i   = B[ci];
            const float b1j   = B[cj];
            const float b1k   = B[ck];
            const float b2_ij = B[10 + ci * 10 + cj];
            const float b2_jk = B[10 + cj * 10 + ck];
            const float b3ijk = B[110 + id];

            float b4v[10];
            #pragma unroll
            for (int l = 0; l < 10; ++l) b4v[l] = wb[1110 + id * 10 + l];

            // Z4 uses OLD a1,a2,a3 (computed before lower levels update)
            #pragma unroll
            for (int l = 0; l < 10; ++l)
                a4[l] += a3 * B[l] + a2 * B[10 + ck * 10 + l]
                       + a1 * B[110 + (cj * 10 + ck) * 10 + l] + b4v[l];
            a3 += a2 * b1k + a1 * b2_jk + b3ijk;
            a2 += a1 * b1j + b2_ij;
            a1 += b1i;
        }
    }

    if (valid) {
        float* ob = out + (size_t)b * SIGSZ;
        float* o4 = ob + 1110 + id * 10;
        #pragma unroll
        for (int l = 0; l < 10; ++l) o4[l] = a4[l];
        ob[110 + id] = a3;
        if (ck == 0)            ob[10 + ci * 10 + cj] = a2;
        if (ck == 0 && cj == 0) ob[ci] = a1;
    }
}

extern "C" void kernel_launch(void* const* d_in, const int* in_sizes, int n_in,
                              void* d_out, int out_size, void* d_ws, size_t ws_size,
                              hipStream_t stream) {
    const float* path = (const float*)d_in[0];   // [64, 512, 10] fp32
    float* out = (float*)d_out;                  // [64, 11110] fp32
    float* ws  = (float*)d_ws;                   // ~12.9 MB used

    float* parts = ws;
    float* dxP   = ws + DXP_OFF;

    sig_prep   <<<dim3(512),  dim3(256), 0, stream>>>(path, dxP);
    sig_partial<<<dim3(1024), dim3(256), 0, stream>>>(path, dxP, parts);
    sig_combine<<<dim3(256),  dim3(256), 0, stream>>>(parts, out);
}